// Round 12
// baseline (402.401 us; speedup 1.0000x reference)
//
#include <hip/hip_runtime.h>
#include <hip/hip_bf16.h>

typedef __attribute__((ext_vector_type(4))) float f32x4;

// ---------------- degree count ----------------
__global__ void count_kernel(const int* __restrict__ dst, int* __restrict__ cnt, int E) {
    int i = blockIdx.x * blockDim.x + threadIdx.x;
    if (i < E) atomicAdd(&cnt[dst[i]], 1);
}

// ---------------- scan1: block-local exclusive scan + dis = 1/sqrt(deg+1) ----------
__global__ void scan1_kernel(const int* __restrict__ cnt, int* __restrict__ offs,
                             int* __restrict__ bsums, float* __restrict__ dis, int n) {
    const int t = threadIdx.x, lane = t & 63, w = t >> 6;
    const int base = blockIdx.x * 1024 + t * 4;
    int v0 = (base + 0 < n) ? cnt[base + 0] : 0;
    int v1 = (base + 1 < n) ? cnt[base + 1] : 0;
    int v2 = (base + 2 < n) ? cnt[base + 2] : 0;
    int v3 = (base + 3 < n) ? cnt[base + 3] : 0;
    if (base + 0 < n) dis[base + 0] = (float)(1.0 / sqrt((double)(v0 + 1)));
    if (base + 1 < n) dis[base + 1] = (float)(1.0 / sqrt((double)(v1 + 1)));
    if (base + 2 < n) dis[base + 2] = (float)(1.0 / sqrt((double)(v2 + 1)));
    if (base + 3 < n) dis[base + 3] = (float)(1.0 / sqrt((double)(v3 + 1)));
    int s = v0 + v1 + v2 + v3;
    int incl = s;
    #pragma unroll
    for (int off = 1; off < 64; off <<= 1) {
        int y = __shfl_up(incl, off);
        if (lane >= off) incl += y;
    }
    __shared__ int wsum[4];
    if (lane == 63) wsum[w] = incl;
    __syncthreads();
    int wbase = 0;
    #pragma unroll
    for (int k = 0; k < 4; ++k) if (k < w) wbase += wsum[k];
    int run = wbase + incl - s;
    if (base + 0 < n) offs[base + 0] = run; run += v0;
    if (base + 1 < n) offs[base + 1] = run; run += v1;
    if (base + 2 < n) offs[base + 2] = run; run += v2;
    if (base + 3 < n) offs[base + 3] = run;
    if (t == 255) bsums[blockIdx.x] = wbase + incl;
}

__global__ void scan2_kernel(int* __restrict__ bsums, int nb) {
    const int t = threadIdx.x, lane = t & 63, w = t >> 6;  // 128 threads
    int s = (t < nb) ? bsums[t] : 0;
    int incl = s;
    #pragma unroll
    for (int off = 1; off < 64; off <<= 1) {
        int y = __shfl_up(incl, off);
        if (lane >= off) incl += y;
    }
    __shared__ int wsum[2];
    if (lane == 63) wsum[w] = incl;
    __syncthreads();
    int wbase = (w == 1) ? wsum[0] : 0;
    if (t < nb) bsums[t] = wbase + incl - s;
}

// scan3: finalize offsets; emit cursor and packed (start,cnt) meta
__global__ void scan3_kernel(const int* __restrict__ offs, const int* __restrict__ bsums,
                             const int* __restrict__ cnt, int* __restrict__ cursor,
                             int2* __restrict__ meta, int n) {
    int i = blockIdx.x * blockDim.x + threadIdx.x;
    if (i < n) {
        int v = offs[i] + bsums[i >> 10];
        cursor[i] = v;
        meta[i] = make_int2(v, cnt[i]);
    }
}

// ---------------- segmented CSR fill (src only; 4B/edge) -------------------------
// R11 lesson: single-pass random 8B scatter across 12.8MB thrashed XCD L2s ->
// 101MB writeback (8x amplification), ~98us. Per-segment the csr slice (1.6MB)
// fits every L2, so lines absorb all slot-writes before one writeback.
__global__ void fill_seg_kernel(const int* __restrict__ ei, int* __restrict__ cursor,
                                int* __restrict__ csr_src, int E, int lo, int hi) {
    const int* src = ei;
    const int* dst = ei + E;
    int i = blockIdx.x * blockDim.x + threadIdx.x;
    const int stride = gridDim.x * blockDim.x;
    for (; i < E; i += stride) {
        const int d = dst[i];
        if (d >= lo && d < hi) {
            const int pos = atomicAdd(&cursor[d], 1);
            csr_src[pos] = src[i];
        }
    }
}

// ---------------- g0 = dis * x (norm-factoring: g = dis*h per layer) -------------
__global__ void gscale_kernel(const float* __restrict__ x, const float* __restrict__ dis,
                              float* __restrict__ g0, int n) {
    int i = blockIdx.x * blockDim.x + threadIdx.x;
    if (i < n) {
        const float d = dis[i];
        float2 v = *(const float2*)(x + 2 * (size_t)i);
        v.x *= d; v.y *= d;
        *(float2*)(g0 + 2 * (size_t)i) = v;
    }
}

// =============== Layer 1: [N,2] -> g1[N,16]. Wave per node. ======================
// agg = dis[node]*(sum g0[src] + g0[node]); out g1 = dis[node]*relu(agg@W1+b1).
__global__ __launch_bounds__(256, 4)
void gcn_l1(const float* __restrict__ g0, const int2* __restrict__ meta,
            const int* __restrict__ csr_src, const float* __restrict__ dis,
            const float* __restrict__ W, const float* __restrict__ B,
            float* __restrict__ g1, int n, int nwaves) {
    const int lane = threadIdx.x & 63;
    const int wid = blockIdx.x * (blockDim.x >> 6) + (threadIdx.x >> 6);
    const int chunk = (n + nwaves - 1) / nwaves;
    const int n0 = wid * chunk, n1 = min(n0 + chunk, n);
    const int o = lane & 15;
    const float w0 = W[o], w1 = W[16 + o], bo = B[o];
    for (int node = n0; node < n1; ++node) {
        const int2 mt = meta[node];
        const int start = mt.x, m = mt.y;
        float a0 = 0.f, a1 = 0.f;
        for (int j = lane; j < m; j += 64) {
            const int s2 = csr_src[start + j];
            const float2 hv = *(const float2*)(g0 + 2 * (size_t)s2);
            a0 += hv.x;
            a1 += hv.y;
        }
        #pragma unroll
        for (int off = 32; off >= 1; off >>= 1) {
            a0 += __shfl_xor(a0, off);
            a1 += __shfl_xor(a1, off);
        }
        const float d0 = dis[node];
        const float2 hs = *(const float2*)(g0 + 2 * (size_t)node);
        a0 = (a0 + hs.x) * d0;
        a1 = (a1 + hs.y) * d0;
        if (lane < 16) {
            const float v = fmaxf(fmaf(a0, w0, fmaf(a1, w1, bo)), 0.f);
            g1[(size_t)node * 16 + o] = d0 * v;
        }
    }
}

// =============== AGG: agg[node] = dis[node]*(sum g[src] + g[node]). ==============
// One wave per node, zero barriers. Dummy slots masked by 0/1 multiplier.
template <int C_IN>
__global__ __launch_bounds__(256, 8)
void agg_kernel(const float* __restrict__ g_in, const int2* __restrict__ meta,
                const int* __restrict__ csr_src, const float* __restrict__ dis,
                float* __restrict__ agg, int n) {
    constexpr int LPR = C_IN / 4;                      // 4, 8, 16
    constexpr int EPW = 64 / LPR;                      // 16, 8, 4
    constexpr int LOGL = (LPR == 4) ? 2 : (LPR == 8) ? 3 : 4;

    const int lane = threadIdx.x & 63;
    const int node = blockIdx.x * 4 + (threadIdx.x >> 6);
    if (node >= n) return;

    const int2 mt = meta[node];
    const int start = mt.x, m = mt.y;
    const int cb = (lane & (LPR - 1)) * 4;
    const int sub = lane >> LOGL;

    float ax = 0.f, ay = 0.f, az = 0.f, aw = 0.f;
    for (int j = sub; j < m; j += 4 * EPW) {
        const bool ok1 = j + 1 * EPW < m, ok2 = j + 2 * EPW < m, ok3 = j + 3 * EPW < m;
        const int ss0 = csr_src[start + j];
        const int ss1 = csr_src[start + (ok1 ? j + 1 * EPW : 0)];
        const int ss2 = csr_src[start + (ok2 ? j + 2 * EPW : 0)];
        const int ss3 = csr_src[start + (ok3 ? j + 3 * EPW : 0)];
        const float m1 = ok1 ? 1.f : 0.f;
        const float m2 = ok2 ? 1.f : 0.f;
        const float m3 = ok3 ? 1.f : 0.f;
        f32x4 h0, h1v, h2v, h3v;
        const float* a0 = g_in + (size_t)ss0 * C_IN + cb;
        const float* a1 = g_in + (size_t)ss1 * C_IN + cb;
        const float* a2 = g_in + (size_t)ss2 * C_IN + cb;
        const float* a3 = g_in + (size_t)ss3 * C_IN + cb;
        asm volatile("global_load_dwordx4 %0, %1, off" : "=v"(h0)  : "v"(a0) : "memory");
        asm volatile("global_load_dwordx4 %0, %1, off" : "=v"(h1v) : "v"(a1) : "memory");
        asm volatile("global_load_dwordx4 %0, %1, off" : "=v"(h2v) : "v"(a2) : "memory");
        asm volatile("global_load_dwordx4 %0, %1, off" : "=v"(h3v) : "v"(a3) : "memory");
        asm volatile("s_waitcnt vmcnt(0)" ::: "memory");
        __builtin_amdgcn_sched_barrier(0);             // rule #18
        ax += h0.x; ay += h0.y; az += h0.z; aw += h0.w;
        ax = fmaf(m1, h1v.x, ax); ay = fmaf(m1, h1v.y, ay);
        az = fmaf(m1, h1v.z, az); aw = fmaf(m1, h1v.w, aw);
        ax = fmaf(m2, h2v.x, ax); ay = fmaf(m2, h2v.y, ay);
        az = fmaf(m2, h2v.z, az); aw = fmaf(m2, h2v.w, aw);
        ax = fmaf(m3, h3v.x, ax); ay = fmaf(m3, h3v.y, ay);
        az = fmaf(m3, h3v.z, az); aw = fmaf(m3, h3v.w, aw);
    }
    #pragma unroll
    for (int off = 32; off >= LPR; off >>= 1) {
        ax += __shfl_xor(ax, off); ay += __shfl_xor(ay, off);
        az += __shfl_xor(az, off); aw += __shfl_xor(aw, off);
    }
    if (lane < LPR) {
        const f32x4 hs = *(const f32x4*)(g_in + (size_t)node * C_IN + cb);
        const float d0 = dis[node];
        ax = (ax + hs.x) * d0; ay = (ay + hs.y) * d0;
        az = (az + hs.z) * d0; aw = (aw + hs.w) * d0;
        f32x4 t; t.x = ax; t.y = ay; t.z = az; t.w = aw;
        *(f32x4*)&agg[(size_t)node * C_IN + cb] = t;
    }
}

// =============== GEMM: g_out = dis*relu(agg @ W + B)  (or FPOOL epilogue). ========
template <int C_IN, int C_OUT, bool FPOOL>
__global__ __launch_bounds__(256, 3)
void gemm_kernel(const float* __restrict__ agg, const float* __restrict__ W,
                 const float* __restrict__ Bias, const float* __restrict__ dis,
                 float* __restrict__ g_out, const int* __restrict__ batchv,
                 float* __restrict__ pooled, int n) {
    constexpr int QW = C_OUT / 16;                 // out-quads per wave: 2,4,8
    constexpr int RPT = QW;                        // rows per thread: 2,4,8
    constexpr int LOGQ = (QW == 8) ? 3 : (QW == 4) ? 2 : 1;
    constexpr int CH = C_IN / 4;                   // f32x4 chunks per agg row
    constexpr int SA = 68;                         // At row stride
    constexpr int SP = 133;                        // sP row stride

    constexpr int W_BYTES = C_IN * C_OUT * 4 + C_OUT * 4;
    constexpr int P_BYTES = FPOOL ? (64 * SP * 4) : 0;
    constexpr int R1 = ((W_BYTES > P_BYTES ? W_BYTES : P_BYTES) + 15) & ~15;
    constexpr int AT_BYTES = C_IN * SA * 4;
    __shared__ char smem[R1 + AT_BYTES];
    __shared__ int sGb[64];
    __shared__ float sDis[64];

    float* sW = (float*)smem;
    float* sB = sW + C_IN * C_OUT;
    float* sP = (float*)smem;                      // overlays sW after k-loop (FPOOL)
    float* sAt = (float*)(smem + R1);

    const int tid = threadIdx.x;
    const int base = blockIdx.x * 64;

    for (int i = tid; i < C_IN * C_OUT / 4; i += 256)
        ((f32x4*)sW)[i] = ((const f32x4*)W)[i];
    if (tid < C_OUT) sB[tid] = Bias[tid];
    {   // stage agg transposed: At[k][row] (zero past n)
        constexpr int RPP = 256 / CH;
        const int r = tid / CH, c0 = tid % CH;
        #pragma unroll
        for (int p = 0; p < 64 / RPP; ++p) {
            const int rr = p * RPP + r;
            const int node = base + rr;
            f32x4 v = {0.f, 0.f, 0.f, 0.f};
            if (node < n) v = *(const f32x4*)&agg[(size_t)node * C_IN + c0 * 4];
            sAt[(c0 * 4 + 0) * SA + rr] = v.x;
            sAt[(c0 * 4 + 1) * SA + rr] = v.y;
            sAt[(c0 * 4 + 2) * SA + rr] = v.z;
            sAt[(c0 * 4 + 3) * SA + rr] = v.w;
        }
    }
    if (FPOOL && tid < 64) sGb[tid] = (base + tid < n) ? batchv[base + tid] : -1;
    if (!FPOOL && tid < 64) sDis[tid] = (base + tid < n) ? dis[base + tid] : 0.f;
    __syncthreads();

    const int w = tid >> 6, l = tid & 63;
    const int j = l & (QW - 1);
    const int rg = l >> LOGQ;
    const int ob = w * (C_OUT / 4) + j * 4;

    f32x4 acc[RPT];
    {
        const f32x4 bv = *(const f32x4*)&sB[ob];
        #pragma unroll
        for (int r = 0; r < RPT; ++r) acc[r] = bv;
    }

    #pragma unroll 4
    for (int k = 0; k < C_IN; ++k) {
        const f32x4 wv = ((const f32x4*)sW)[k * (C_OUT / 4) + (ob >> 2)];
        float av[RPT];
        if constexpr (RPT == 8) {
            const f32x4 a0 = *(const f32x4*)&sAt[k * SA + rg * 8];
            const f32x4 a1 = *(const f32x4*)&sAt[k * SA + rg * 8 + 4];
            av[0] = a0.x; av[1] = a0.y; av[2] = a0.z; av[3] = a0.w;
            av[4] = a1.x; av[5] = a1.y; av[6] = a1.z; av[7] = a1.w;
        } else if constexpr (RPT == 4) {
            const f32x4 a0 = *(const f32x4*)&sAt[k * SA + rg * 4];
            av[0] = a0.x; av[1] = a0.y; av[2] = a0.z; av[3] = a0.w;
        } else {
            const float2 a0 = *(const float2*)&sAt[k * SA + rg * 2];
            av[0] = a0.x; av[1] = a0.y;
        }
        #pragma unroll
        for (int r = 0; r < RPT; ++r) {
            acc[r].x = fmaf(av[r], wv.x, acc[r].x);
            acc[r].y = fmaf(av[r], wv.y, acc[r].y);
            acc[r].z = fmaf(av[r], wv.z, acc[r].z);
            acc[r].w = fmaf(av[r], wv.w, acc[r].w);
        }
    }

    if constexpr (!FPOOL) {
        #pragma unroll
        for (int r = 0; r < RPT; ++r) {
            const int row = rg * RPT + r;
            const int node = base + row;
            if (node < n) {
                const float sd = sDis[row];
                f32x4 o;
                o.x = sd * fmaxf(acc[r].x, 0.f); o.y = sd * fmaxf(acc[r].y, 0.f);
                o.z = sd * fmaxf(acc[r].z, 0.f); o.w = sd * fmaxf(acc[r].w, 0.f);
                *(f32x4*)&g_out[(size_t)node * C_OUT + ob] = o;
            }
        }
    } else {
        __syncthreads();                           // k-loop reads of sW done (overlay!)
        #pragma unroll
        for (int r = 0; r < RPT; ++r) {
            const int row = rg * RPT + r;
            sP[row * SP + ob + 0] = fmaxf(acc[r].x, 0.f);
            sP[row * SP + ob + 1] = fmaxf(acc[r].y, 0.f);
            sP[row * SP + ob + 2] = fmaxf(acc[r].z, 0.f);
            sP[row * SP + ob + 3] = fmaxf(acc[r].w, 0.f);
        }
        __syncthreads();
        if (tid < 128) {                           // one thread per out column
            const int c = tid;
            int curg = -1; float run = 0.f;
            for (int r = 0; r < 64; ++r) {
                const int gb = sGb[r];
                if (gb < 0) continue;
                const float v = sP[r * SP + c];
                if (gb != curg) {
                    if (curg >= 0)
                        atomicMax((int*)&pooled[(size_t)curg * 128 + c], __float_as_int(run));
                    curg = gb; run = v;
                } else {
                    run = fmaxf(run, v);
                }
            }
            if (curg >= 0)
                atomicMax((int*)&pooled[(size_t)curg * 128 + c], __float_as_int(run));
        }
    }
}

// ---------------- MLP head: relu(pooled @ W5 + b5) @ W6 + b6 ----------------
__global__ void mlp_kernel(const float* __restrict__ pooled,
                           const float* __restrict__ W5, const float* __restrict__ b5,
                           const float* __restrict__ W6, const float* __restrict__ b6,
                           float* __restrict__ out) {
    const int g = blockIdx.x;
    const int t = threadIdx.x;  // 64 threads
    __shared__ float row[128];
    __shared__ float hid[64];
    row[t] = pooled[g * 128 + t];
    row[64 + t] = pooled[g * 128 + 64 + t];
    __syncthreads();
    float v = b5[t];
    #pragma unroll 8
    for (int c = 0; c < 128; ++c) v = fmaf(row[c], W5[c * 64 + t], v);
    hid[t] = fmaxf(v, 0.f);
    __syncthreads();
    if (t < 10) {
        float o = b6[t];
        #pragma unroll 8
        for (int c = 0; c < 64; ++c) o = fmaf(hid[c], W6[c * 10 + t], o);
        out[g * 10 + t] = o;
    }
}

extern "C" void kernel_launch(void* const* d_in, const int* in_sizes, int n_in,
                              void* d_out, int out_size, void* d_ws, size_t ws_size,
                              hipStream_t stream) {
    const float* x     = (const float*)d_in[0];
    const int*   ei    = (const int*)d_in[1];
    const int*   batch = (const int*)d_in[2];
    const float* W1 = (const float*)d_in[3];  const float* b1 = (const float*)d_in[4];
    const float* W2 = (const float*)d_in[5];  const float* b2 = (const float*)d_in[6];
    const float* W3 = (const float*)d_in[7];  const float* b3 = (const float*)d_in[8];
    const float* W4 = (const float*)d_in[9];  const float* b4 = (const float*)d_in[10];
    const float* W5 = (const float*)d_in[11]; const float* b5 = (const float*)d_in[12];
    const float* W6 = (const float*)d_in[13]; const float* b6 = (const float*)d_in[14];
    float* out = (float*)d_out;

    const int N = in_sizes[0] / 2;       // 100000
    const int E = in_sizes[1] / 2;       // 1600000
    const int G = out_size / 10;         // 512
    const int* dst = ei + E;

    // workspace layout (~80 MB)
    char* p = (char*)d_ws;
    auto take = [&](size_t bytes) -> void* {
        void* r = (void*)p;
        p += (bytes + 255) & ~(size_t)255;
        return r;
    };
    int*   cnt      = (int*)take((size_t)N * 4);
    int*   offs     = (int*)take((size_t)N * 4);
    int*   cursor   = (int*)take((size_t)N * 4);
    int*   bsums    = (int*)take(512 * 4);
    float* dis      = (float*)take((size_t)N * 4);
    int2*  meta     = (int2*)take((size_t)N * 8);
    int*   csr_src  = (int*)take((size_t)E * 4);
    float* g0       = (float*)take((size_t)N * 2 * 4);
    float* g1       = (float*)take((size_t)N * 16 * 4);
    float* g2       = (float*)take((size_t)N * 32 * 4);
    float* g3       = (float*)take((size_t)N * 64 * 4);
    float* aggb     = (float*)take((size_t)N * 64 * 4);
    float* pooled   = (float*)take((size_t)G * 128 * 4);

    hipMemsetAsync(cnt, 0, (size_t)N * 4, stream);
    hipMemsetAsync(pooled, 0, (size_t)G * 128 * 4, stream);

    count_kernel<<<(E + 255) / 256, 256, 0, stream>>>(dst, cnt, E);

    const int NB = (N + 1023) / 1024;    // 98
    scan1_kernel<<<NB, 256, 0, stream>>>(cnt, offs, bsums, dis, N);
    scan2_kernel<<<1, 128, 0, stream>>>(bsums, NB);
    scan3_kernel<<<(N + 255) / 256, 256, 0, stream>>>(offs, bsums, cnt, cursor, meta, N);

    // segmented CSR fill: each segment's csr slice (~1.6MB) fits XCD L2
    const int NSEG = 4;
    for (int s = 0; s < NSEG; ++s) {
        const int lo = (int)(((long long)N * s) / NSEG);
        const int hi = (int)(((long long)N * (s + 1)) / NSEG);
        fill_seg_kernel<<<2048, 256, 0, stream>>>(ei, cursor, csr_src, E, lo, hi);
    }

    gscale_kernel<<<(N + 255) / 256, 256, 0, stream>>>(x, dis, g0, N);

    gcn_l1<<<2048, 256, 0, stream>>>(g0, meta, csr_src, dis, W1, b1, g1, N, 2048 * 4);

    const int ABLK = (N + 3) / 4;        // 4 waves per 256-thr block, 1 node each
    const int GBLK = (N + 63) / 64;      // 64-node GEMM tiles

    agg_kernel<16><<<ABLK, 256, 0, stream>>>(g1, meta, csr_src, dis, aggb, N);
    gemm_kernel<16, 32, false><<<GBLK, 256, 0, stream>>>(aggb, W2, b2, dis, g2, nullptr, nullptr, N);

    agg_kernel<32><<<ABLK, 256, 0, stream>>>(g2, meta, csr_src, dis, aggb, N);
    gemm_kernel<32, 64, false><<<GBLK, 256, 0, stream>>>(aggb, W3, b3, dis, g3, nullptr, nullptr, N);

    agg_kernel<64><<<ABLK, 256, 0, stream>>>(g3, meta, csr_src, dis, aggb, N);
    gemm_kernel<64, 128, true><<<GBLK, 256, 0, stream>>>(aggb, W4, b4, dis, nullptr, batch, pooled, N);

    mlp_kernel<<<G, 64, 0, stream>>>(pooled, W5, b5, W6, b6, out);
}

// Round 13
// 264.773 us; speedup vs baseline: 1.5198x; 1.5198x over previous
//
#include <hip/hip_runtime.h>
#include <hip/hip_bf16.h>

typedef __attribute__((ext_vector_type(4))) float f32x4;

#define EPB 4096      // edges per partition block
#define NBKT 196      // ceil(100000/512) buckets of 512 nodes
#define BCAP 10240    // arena capacity per bucket (mean 8192, +22 sigma)

// =============== Phase B: partition edges into per-bucket arenas ================
// All per-edge work uses LDS atomics; global atomics only 1 per (block,bucket).
__global__ __launch_bounds__(256)
void partition_kernel(const int* __restrict__ ei, int E,
                      int* __restrict__ bktCur, int* __restrict__ arena) {
    __shared__ int sHist[256];       // 196 used (padded to 256)
    __shared__ int sScan[256];
    __shared__ int sAdj[256];
    __shared__ int2 sEdges[EPB];     // 32 KB staging
    const int t = threadIdx.x;
    const int e0 = blockIdx.x * EPB;
    const int ecnt = min(EPB, E - e0);
    const int* src = ei;
    const int* dst = ei + E;

    sHist[t] = 0;
    __syncthreads();
    for (int k = t; k < ecnt; k += 256) {        // stage + histogram
        const int s = src[e0 + k], d = dst[e0 + k];
        sEdges[k] = make_int2(s, d);
        atomicAdd(&sHist[d >> 9], 1);
    }
    __syncthreads();
    const int v = sHist[t];                      // block-exclusive scan (Hillis-Steele)
    sScan[t] = v;
    __syncthreads();
    #pragma unroll
    for (int off = 1; off < 256; off <<= 1) {
        const int y = (t >= off) ? sScan[t - off] : 0;
        __syncthreads();
        sScan[t] += y;
        __syncthreads();
    }
    const int excl = sScan[t] - v;
    if (t < NBKT && v > 0) {                     // reserve arena space (1 atomic/bucket)
        const int g = atomicAdd(&bktCur[t], v);
        sAdj[t] = t * BCAP + g - excl;           // sorted pos p -> arena slot sAdj[b]+p
    }
    sHist[t] = excl;                             // reuse as local placement cursor
    __syncthreads();
    for (int k = t; k < ecnt; k += 256) {        // place packed (src<<9 | d&511)
        const int2 e = sEdges[k];
        const int b = e.y >> 9;
        const int p = atomicAdd(&sHist[b], 1);
        arena[sAdj[b] + p] = (e.x << 9) | (e.y & 511);
    }
}

// =============== Phase C: per-bucket CSR build + meta + dis + g0 = dis*x =========
__global__ __launch_bounds__(512)
void bucket_csr_kernel(const int* __restrict__ arena, const int* __restrict__ bktCur,
                       int* __restrict__ csr_src, int2* __restrict__ meta,
                       float* __restrict__ dis, const float* __restrict__ x,
                       float* __restrict__ g0, int n) {
    __shared__ int sHist[512];
    __shared__ int sScan[512];
    const int t = threadIdx.x;
    const int b = blockIdx.x;
    const int base = b * BCAP;
    const int cnt_b = min(bktCur[b], BCAP);

    sHist[t] = 0;
    __syncthreads();
    for (int e = t; e < cnt_b; e += 512)
        atomicAdd(&sHist[arena[base + e] & 511], 1);
    __syncthreads();
    const int v = sHist[t];
    sScan[t] = v;
    __syncthreads();
    #pragma unroll
    for (int off = 1; off < 512; off <<= 1) {
        const int y = (t >= off) ? sScan[t - off] : 0;
        __syncthreads();
        sScan[t] += y;
        __syncthreads();
    }
    const int excl = sScan[t] - v;
    const int node = b * 512 + t;
    if (node < n) {
        meta[node] = make_int2(base + excl, v);
        const float d = (float)(1.0 / sqrt((double)(v + 1)));
        dis[node] = d;
        float2 xv = *(const float2*)(x + 2 * (size_t)node);
        xv.x *= d; xv.y *= d;
        *(float2*)(g0 + 2 * (size_t)node) = xv;
    }
    sHist[t] = excl;                             // local cursor
    __syncthreads();
    for (int e = t; e < cnt_b; e += 512) {
        const int pv = arena[base + e];
        const int p = atomicAdd(&sHist[pv & 511], 1);
        csr_src[base + p] = pv >> 9;             // random 4B within 40KB window: L2-hot
    }
}

// =============== Layer 1: [N,2] -> g1[N,16]. Wave per node. ======================
// agg = dis[node]*(sum g0[src] + g0[node]); out g1 = dis[node]*relu(agg@W1+b1).
__global__ __launch_bounds__(256, 4)
void gcn_l1(const float* __restrict__ g0, const int2* __restrict__ meta,
            const int* __restrict__ csr_src, const float* __restrict__ dis,
            const float* __restrict__ W, const float* __restrict__ B,
            float* __restrict__ g1, int n, int nwaves) {
    const int lane = threadIdx.x & 63;
    const int wid = blockIdx.x * (blockDim.x >> 6) + (threadIdx.x >> 6);
    const int chunk = (n + nwaves - 1) / nwaves;
    const int n0 = wid * chunk, n1 = min(n0 + chunk, n);
    const int o = lane & 15;
    const float w0 = W[o], w1 = W[16 + o], bo = B[o];
    for (int node = n0; node < n1; ++node) {
        const int2 mt = meta[node];
        const int start = mt.x, m = mt.y;
        float a0 = 0.f, a1 = 0.f;
        for (int j = lane; j < m; j += 64) {
            const int s2 = csr_src[start + j];
            const float2 hv = *(const float2*)(g0 + 2 * (size_t)s2);
            a0 += hv.x;
            a1 += hv.y;
        }
        #pragma unroll
        for (int off = 32; off >= 1; off >>= 1) {
            a0 += __shfl_xor(a0, off);
            a1 += __shfl_xor(a1, off);
        }
        const float d0 = dis[node];
        const float2 hs = *(const float2*)(g0 + 2 * (size_t)node);
        a0 = (a0 + hs.x) * d0;
        a1 = (a1 + hs.y) * d0;
        if (lane < 16) {
            const float v = fmaxf(fmaf(a0, w0, fmaf(a1, w1, bo)), 0.f);
            g1[(size_t)node * 16 + o] = d0 * v;
        }
    }
}

// =============== AGG: agg[node] = dis[node]*(sum g[src] + g[node]). ==============
template <int C_IN>
__global__ __launch_bounds__(256, 8)
void agg_kernel(const float* __restrict__ g_in, const int2* __restrict__ meta,
                const int* __restrict__ csr_src, const float* __restrict__ dis,
                float* __restrict__ agg, int n) {
    constexpr int LPR = C_IN / 4;                      // 4, 8, 16
    constexpr int EPW = 64 / LPR;                      // 16, 8, 4
    constexpr int LOGL = (LPR == 4) ? 2 : (LPR == 8) ? 3 : 4;

    const int lane = threadIdx.x & 63;
    const int node = blockIdx.x * 4 + (threadIdx.x >> 6);
    if (node >= n) return;

    const int2 mt = meta[node];
    const int start = mt.x, m = mt.y;
    const int cb = (lane & (LPR - 1)) * 4;
    const int sub = lane >> LOGL;

    float ax = 0.f, ay = 0.f, az = 0.f, aw = 0.f;
    for (int j = sub; j < m; j += 4 * EPW) {
        const bool ok1 = j + 1 * EPW < m, ok2 = j + 2 * EPW < m, ok3 = j + 3 * EPW < m;
        const int ss0 = csr_src[start + j];
        const int ss1 = csr_src[start + (ok1 ? j + 1 * EPW : 0)];
        const int ss2 = csr_src[start + (ok2 ? j + 2 * EPW : 0)];
        const int ss3 = csr_src[start + (ok3 ? j + 3 * EPW : 0)];
        const float m1 = ok1 ? 1.f : 0.f;
        const float m2 = ok2 ? 1.f : 0.f;
        const float m3 = ok3 ? 1.f : 0.f;
        f32x4 h0, h1v, h2v, h3v;
        const float* a0 = g_in + (size_t)ss0 * C_IN + cb;
        const float* a1 = g_in + (size_t)ss1 * C_IN + cb;
        const float* a2 = g_in + (size_t)ss2 * C_IN + cb;
        const float* a3 = g_in + (size_t)ss3 * C_IN + cb;
        asm volatile("global_load_dwordx4 %0, %1, off" : "=v"(h0)  : "v"(a0) : "memory");
        asm volatile("global_load_dwordx4 %0, %1, off" : "=v"(h1v) : "v"(a1) : "memory");
        asm volatile("global_load_dwordx4 %0, %1, off" : "=v"(h2v) : "v"(a2) : "memory");
        asm volatile("global_load_dwordx4 %0, %1, off" : "=v"(h3v) : "v"(a3) : "memory");
        asm volatile("s_waitcnt vmcnt(0)" ::: "memory");
        __builtin_amdgcn_sched_barrier(0);             // rule #18
        ax += h0.x; ay += h0.y; az += h0.z; aw += h0.w;
        ax = fmaf(m1, h1v.x, ax); ay = fmaf(m1, h1v.y, ay);
        az = fmaf(m1, h1v.z, az); aw = fmaf(m1, h1v.w, aw);
        ax = fmaf(m2, h2v.x, ax); ay = fmaf(m2, h2v.y, ay);
        az = fmaf(m2, h2v.z, az); aw = fmaf(m2, h2v.w, aw);
        ax = fmaf(m3, h3v.x, ax); ay = fmaf(m3, h3v.y, ay);
        az = fmaf(m3, h3v.z, az); aw = fmaf(m3, h3v.w, aw);
    }
    #pragma unroll
    for (int off = 32; off >= LPR; off >>= 1) {
        ax += __shfl_xor(ax, off); ay += __shfl_xor(ay, off);
        az += __shfl_xor(az, off); aw += __shfl_xor(aw, off);
    }
    if (lane < LPR) {
        const f32x4 hs = *(const f32x4*)(g_in + (size_t)node * C_IN + cb);
        const float d0 = dis[node];
        ax = (ax + hs.x) * d0; ay = (ay + hs.y) * d0;
        az = (az + hs.z) * d0; aw = (aw + hs.w) * d0;
        f32x4 t; t.x = ax; t.y = ay; t.z = az; t.w = aw;
        *(f32x4*)&agg[(size_t)node * C_IN + cb] = t;
    }
}

// =============== GEMM: g_out = dis*relu(agg @ W + B)  (or FPOOL epilogue). ========
template <int C_IN, int C_OUT, bool FPOOL>
__global__ __launch_bounds__(256, 3)
void gemm_kernel(const float* __restrict__ agg, const float* __restrict__ W,
                 const float* __restrict__ Bias, const float* __restrict__ dis,
                 float* __restrict__ g_out, const int* __restrict__ batchv,
                 float* __restrict__ pooled, int n) {
    constexpr int QW = C_OUT / 16;                 // out-quads per wave: 2,4,8
    constexpr int RPT = QW;                        // rows per thread: 2,4,8
    constexpr int LOGQ = (QW == 8) ? 3 : (QW == 4) ? 2 : 1;
    constexpr int CH = C_IN / 4;                   // f32x4 chunks per agg row
    constexpr int SA = 68;                         // At row stride
    constexpr int SP = 133;                        // sP row stride

    constexpr int W_BYTES = C_IN * C_OUT * 4 + C_OUT * 4;
    constexpr int P_BYTES = FPOOL ? (64 * SP * 4) : 0;
    constexpr int R1 = ((W_BYTES > P_BYTES ? W_BYTES : P_BYTES) + 15) & ~15;
    constexpr int AT_BYTES = C_IN * SA * 4;
    __shared__ char smem[R1 + AT_BYTES];
    __shared__ int sGb[64];
    __shared__ float sDis[64];

    float* sW = (float*)smem;
    float* sB = sW + C_IN * C_OUT;
    float* sP = (float*)smem;                      // overlays sW after k-loop (FPOOL)
    float* sAt = (float*)(smem + R1);

    const int tid = threadIdx.x;
    const int base = blockIdx.x * 64;

    for (int i = tid; i < C_IN * C_OUT / 4; i += 256)
        ((f32x4*)sW)[i] = ((const f32x4*)W)[i];
    if (tid < C_OUT) sB[tid] = Bias[tid];
    {   // stage agg transposed: At[k][row] (zero past n)
        constexpr int RPP = 256 / CH;
        const int r = tid / CH, c0 = tid % CH;
        #pragma unroll
        for (int p = 0; p < 64 / RPP; ++p) {
            const int rr = p * RPP + r;
            const int node = base + rr;
            f32x4 v = {0.f, 0.f, 0.f, 0.f};
            if (node < n) v = *(const f32x4*)&agg[(size_t)node * C_IN + c0 * 4];
            sAt[(c0 * 4 + 0) * SA + rr] = v.x;
            sAt[(c0 * 4 + 1) * SA + rr] = v.y;
            sAt[(c0 * 4 + 2) * SA + rr] = v.z;
            sAt[(c0 * 4 + 3) * SA + rr] = v.w;
        }
    }
    if (FPOOL && tid < 64) sGb[tid] = (base + tid < n) ? batchv[base + tid] : -1;
    if (!FPOOL && tid < 64) sDis[tid] = (base + tid < n) ? dis[base + tid] : 0.f;
    __syncthreads();

    const int w = tid >> 6, l = tid & 63;
    const int j = l & (QW - 1);
    const int rg = l >> LOGQ;
    const int ob = w * (C_OUT / 4) + j * 4;

    f32x4 acc[RPT];
    {
        const f32x4 bv = *(const f32x4*)&sB[ob];
        #pragma unroll
        for (int r = 0; r < RPT; ++r) acc[r] = bv;
    }

    #pragma unroll 4
    for (int k = 0; k < C_IN; ++k) {
        const f32x4 wv = ((const f32x4*)sW)[k * (C_OUT / 4) + (ob >> 2)];
        float av[RPT];
        if constexpr (RPT == 8) {
            const f32x4 a0 = *(const f32x4*)&sAt[k * SA + rg * 8];
            const f32x4 a1 = *(const f32x4*)&sAt[k * SA + rg * 8 + 4];
            av[0] = a0.x; av[1] = a0.y; av[2] = a0.z; av[3] = a0.w;
            av[4] = a1.x; av[5] = a1.y; av[6] = a1.z; av[7] = a1.w;
        } else if constexpr (RPT == 4) {
            const f32x4 a0 = *(const f32x4*)&sAt[k * SA + rg * 4];
            av[0] = a0.x; av[1] = a0.y; av[2] = a0.z; av[3] = a0.w;
        } else {
            const float2 a0 = *(const float2*)&sAt[k * SA + rg * 2];
            av[0] = a0.x; av[1] = a0.y;
        }
        #pragma unroll
        for (int r = 0; r < RPT; ++r) {
            acc[r].x = fmaf(av[r], wv.x, acc[r].x);
            acc[r].y = fmaf(av[r], wv.y, acc[r].y);
            acc[r].z = fmaf(av[r], wv.z, acc[r].z);
            acc[r].w = fmaf(av[r], wv.w, acc[r].w);
        }
    }

    if constexpr (!FPOOL) {
        #pragma unroll
        for (int r = 0; r < RPT; ++r) {
            const int row = rg * RPT + r;
            const int node = base + row;
            if (node < n) {
                const float sd = sDis[row];
                f32x4 o;
                o.x = sd * fmaxf(acc[r].x, 0.f); o.y = sd * fmaxf(acc[r].y, 0.f);
                o.z = sd * fmaxf(acc[r].z, 0.f); o.w = sd * fmaxf(acc[r].w, 0.f);
                *(f32x4*)&g_out[(size_t)node * C_OUT + ob] = o;
            }
        }
    } else {
        __syncthreads();                           // k-loop reads of sW done (overlay!)
        #pragma unroll
        for (int r = 0; r < RPT; ++r) {
            const int row = rg * RPT + r;
            sP[row * SP + ob + 0] = fmaxf(acc[r].x, 0.f);
            sP[row * SP + ob + 1] = fmaxf(acc[r].y, 0.f);
            sP[row * SP + ob + 2] = fmaxf(acc[r].z, 0.f);
            sP[row * SP + ob + 3] = fmaxf(acc[r].w, 0.f);
        }
        __syncthreads();
        if (tid < 128) {                           // one thread per out column
            const int c = tid;
            int curg = -1; float run = 0.f;
            for (int r = 0; r < 64; ++r) {
                const int gb = sGb[r];
                if (gb < 0) continue;
                const float v = sP[r * SP + c];
                if (gb != curg) {
                    if (curg >= 0)
                        atomicMax((int*)&pooled[(size_t)curg * 128 + c], __float_as_int(run));
                    curg = gb; run = v;
                } else {
                    run = fmaxf(run, v);
                }
            }
            if (curg >= 0)
                atomicMax((int*)&pooled[(size_t)curg * 128 + c], __float_as_int(run));
        }
    }
}

// ---------------- MLP head: relu(pooled @ W5 + b5) @ W6 + b6 ----------------
__global__ void mlp_kernel(const float* __restrict__ pooled,
                           const float* __restrict__ W5, const float* __restrict__ b5,
                           const float* __restrict__ W6, const float* __restrict__ b6,
                           float* __restrict__ out) {
    const int g = blockIdx.x;
    const int t = threadIdx.x;  // 64 threads
    __shared__ float row[128];
    __shared__ float hid[64];
    row[t] = pooled[g * 128 + t];
    row[64 + t] = pooled[g * 128 + 64 + t];
    __syncthreads();
    float v = b5[t];
    #pragma unroll 8
    for (int c = 0; c < 128; ++c) v = fmaf(row[c], W5[c * 64 + t], v);
    hid[t] = fmaxf(v, 0.f);
    __syncthreads();
    if (t < 10) {
        float o = b6[t];
        #pragma unroll 8
        for (int c = 0; c < 64; ++c) o = fmaf(hid[c], W6[c * 10 + t], o);
        out[g * 10 + t] = o;
    }
}

extern "C" void kernel_launch(void* const* d_in, const int* in_sizes, int n_in,
                              void* d_out, int out_size, void* d_ws, size_t ws_size,
                              hipStream_t stream) {
    const float* x     = (const float*)d_in[0];
    const int*   ei    = (const int*)d_in[1];
    const int*   batch = (const int*)d_in[2];
    const float* W1 = (const float*)d_in[3];  const float* b1 = (const float*)d_in[4];
    const float* W2 = (const float*)d_in[5];  const float* b2 = (const float*)d_in[6];
    const float* W3 = (const float*)d_in[7];  const float* b3 = (const float*)d_in[8];
    const float* W4 = (const float*)d_in[9];  const float* b4 = (const float*)d_in[10];
    const float* W5 = (const float*)d_in[11]; const float* b5 = (const float*)d_in[12];
    const float* W6 = (const float*)d_in[13]; const float* b6 = (const float*)d_in[14];
    float* out = (float*)d_out;

    const int N = in_sizes[0] / 2;       // 100000
    const int E = in_sizes[1] / 2;       // 1600000
    const int G = out_size / 10;         // 512

    // workspace layout (~90 MB)
    char* p = (char*)d_ws;
    auto take = [&](size_t bytes) -> void* {
        void* r = (void*)p;
        p += (bytes + 255) & ~(size_t)255;
        return r;
    };
    int*   bktCur   = (int*)take(NBKT * 4);
    int*   arena    = (int*)take((size_t)NBKT * BCAP * 4);   // 8 MB
    int*   csr_src  = (int*)take((size_t)NBKT * BCAP * 4);   // 8 MB
    float* dis      = (float*)take((size_t)N * 4);
    int2*  meta     = (int2*)take((size_t)N * 8);
    float* g0       = (float*)take((size_t)N * 2 * 4);
    float* g1       = (float*)take((size_t)N * 16 * 4);
    float* g2       = (float*)take((size_t)N * 32 * 4);
    float* g3       = (float*)take((size_t)N * 64 * 4);
    float* aggb     = (float*)take((size_t)N * 64 * 4);
    float* pooled   = (float*)take((size_t)G * 128 * 4);

    hipMemsetAsync(bktCur, 0, NBKT * 4, stream);
    hipMemsetAsync(pooled, 0, (size_t)G * 128 * 4, stream);

    const int PBLK = (E + EPB - 1) / EPB;    // 391
    partition_kernel<<<PBLK, 256, 0, stream>>>(ei, E, bktCur, arena);
    bucket_csr_kernel<<<NBKT, 512, 0, stream>>>(arena, bktCur, csr_src, meta, dis, x, g0, N);

    gcn_l1<<<2048, 256, 0, stream>>>(g0, meta, csr_src, dis, W1, b1, g1, N, 2048 * 4);

    const int ABLK = (N + 3) / 4;        // 4 waves per 256-thr block, 1 node each
    const int GBLK = (N + 63) / 64;      // 64-node GEMM tiles

    agg_kernel<16><<<ABLK, 256, 0, stream>>>(g1, meta, csr_src, dis, aggb, N);
    gemm_kernel<16, 32, false><<<GBLK, 256, 0, stream>>>(aggb, W2, b2, dis, g2, nullptr, nullptr, N);

    agg_kernel<32><<<ABLK, 256, 0, stream>>>(g2, meta, csr_src, dis, aggb, N);
    gemm_kernel<32, 64, false><<<GBLK, 256, 0, stream>>>(aggb, W3, b3, dis, g3, nullptr, nullptr, N);

    agg_kernel<64><<<ABLK, 256, 0, stream>>>(g3, meta, csr_src, dis, aggb, N);
    gemm_kernel<64, 128, true><<<GBLK, 256, 0, stream>>>(aggb, W4, b4, dis, nullptr, batch, pooled, N);

    mlp_kernel<<<G, 64, 0, stream>>>(pooled, W5, b5, W6, b6, out);
}